// Round 1
// 92.065 us; speedup vs baseline: 1.0871x; 1.0871x over previous
//
#include <hip/hip_runtime.h>

// Problem constants (B, L, H, HS, OUT) = (4, 512, 768, 64, 16)
#define Bc   4
#define Lc   512
#define Hc   768
#define HSc  64
#define OUTc 16
#define Pc   131328   // L*(L+1)/2
#define NTOK 2048     // B*L
#define XPITCH 776    // 768 + 8 bf16 pad -> 16B-aligned rows, banks spread

typedef float  floatx4 __attribute__((ext_vector_type(4)));
typedef short  bf16x8  __attribute__((ext_vector_type(8)));   // 8 bf16 in 4 VGPRs
typedef float  f32x4   __attribute__((ext_vector_type(4)));

// ws layout (floats): q@0 [131072], k@131072 [131072], A@262144 [32768], E@294912 [32768]

__device__ __forceinline__ unsigned short f2bf(float f) {
    unsigned int u = __float_as_uint(f);
    return (unsigned short)((u + 0x7FFFu + ((u >> 16) & 1u)) >> 16);   // RNE
}

// Fused prep + QK-GEMM + A/E projection.
// Grid 128 x 512 thr (8 waves). Block = 16-token tile (m0 = bx*16).
// Waves 0..3 compute q cols w*16..w*16+15; waves 4..7 compute k cols.
// A-fragments come from an LDS bf16 x-tile (staged once, coalesced float4 +
// RNE convert). B-fragments stream straight from Wq/Wk global (quad-coalesced
// dword loads, L2-resident 0.4 MB), converted in-register -> no Wt round-trip.
// Epilogue: q/k (+bias) -> global + LDS; then the A/E projection runs in-block
// (identical fp32 accumulation order to the old ae_kernel).
// MFMA layouts (m89/m91): A[m=lane&15][k=quad*8+j]; B[k=quad*8+j][n=lane&15];
// D: col=lane&15, row=quad*4+reg.
__global__ __launch_bounds__(512) void qkae_kernel(
    const float* __restrict__ x, const float* __restrict__ Wq,
    const float* __restrict__ Wk, const float* __restrict__ bq,
    const float* __restrict__ bk, const float* __restrict__ Wb,
    const float* __restrict__ bb,
    float* __restrict__ qws, float* __restrict__ kws,
    float* __restrict__ Aws, float* __restrict__ Ews)
{
    __shared__ alignas(16) unsigned short xs[16 * XPITCH];  // 24.25 KB
    __shared__ float lWb[256 * OUTc];                       // 16 KB
    __shared__ float lqk[16][128];                          // 8 KB

    const int tid  = threadIdx.x;
    const int m0   = blockIdx.x * 16;
    const int w    = tid >> 6;
    const int lane = tid & 63;
    const int l15  = lane & 15;
    const int quad = lane >> 4;
    const bool isq = (w < 4);
    const int  wn  = isq ? w : (w - 4);
    const int  nq  = wn * 16 + l15;          // output col within q (or k) half

    // stage Wb (4096 floats)
    #pragma unroll
    for (int i = 0; i < 8; ++i) lWb[tid + i * 512] = Wb[tid + i * 512];

    // stage x tile as bf16 into padded LDS rows (3072 float4 total)
    {
        const float4* xg = (const float4*)(x + (size_t)m0 * Hc);
        #pragma unroll
        for (int i = 0; i < 6; ++i) {
            const int idx = tid + i * 512;
            const int r   = idx / 192;           // row 0..15
            const int c4  = idx - r * 192;       // float4 col 0..191
            const float4 v = xg[idx];
            *(ushort4*)(xs + r * XPITCH + c4 * 4) =
                make_ushort4(f2bf(v.x), f2bf(v.y), f2bf(v.z), f2bf(v.w));
        }
    }
    __syncthreads();

    const float* bsrc = isq ? Wq : Wk;
    const unsigned short* ap = xs + l15 * XPITCH + quad * 8;

    f32x4 acc = {0.f, 0.f, 0.f, 0.f};
    #pragma unroll 4
    for (int k0 = 0; k0 < Hc; k0 += 32) {
        const bf16x8 af = *(const bf16x8*)(ap + k0);       // ds_read_b128
        const int kb = k0 + quad * 8;
        bf16x8 bf;
        #pragma unroll
        for (int j = 0; j < 8; ++j)                        // quad-coalesced dwords
            bf[j] = (short)f2bf(bsrc[(kb + j) * HSc + nq]);
        acc = __builtin_amdgcn_mfma_f32_16x16x32_bf16(af, bf, acc, 0, 0, 0);
    }

    const float bias = isq ? bq[nq] : bk[nq];
    float* dst = isq ? qws : kws;
    const int cbase = isq ? nq : (64 + nq);
    #pragma unroll
    for (int r = 0; r < 4; ++r) {
        const int t = quad * 4 + r;
        const float v = acc[r] + bias;
        dst[(size_t)(m0 + t) * HSc + nq] = v;
        lqk[t][cbase] = v;
    }
    __syncthreads();

    // A/E projection: 32 threads per token (16 do A, 16 do E) — same math
    // order as the previous standalone ae_kernel.
    const int t   = tid >> 5;        // token 0..15
    const int c   = tid & 31;
    const int tok = m0 + t;
    const float* row = lqk[t];
    if (c < 16) {
        float a = 0.f;
        #pragma unroll 8
        for (int h = 0; h < 64; ++h) a += row[h] * lWb[h * OUTc + c];
        Aws[(size_t)tok * OUTc + c] = a;
    } else {
        const int o = c - 16;
        float ev = bb[o];
        #pragma unroll 8
        for (int h = 0; h < 64; ++h) {
            ev += row[h]      * lWb[(128 + h) * OUTc + o];
            ev += row[64 + h] * (lWb[(64 + h) * OUTc + o] + lWb[(192 + h) * OUTc + o]);
        }
        Ews[(size_t)tok * OUTc + o] = ev;
    }
}

// Pair kernel: tiled as before (16 s x 64 e per block), but grid holds only
// the 144 active upper-triangular tiles per batch (decoded in-kernel) instead
// of 256 with 112 dead early-exit blocks.
// Grid (144, 4): x = linear tile id, y = batch.
__global__ __launch_bounds__(256) void pair_kernel(
    const float* __restrict__ qws, const float* __restrict__ kws,
    const float* __restrict__ Aws, const float* __restrict__ Ews,
    float* __restrict__ out)
{
    // decode linear tile id -> (i = s-tile 0..31, j = e-tile 0..7), j >= i>>2
    int n = blockIdx.x;
    int g = 0;
    int cnt = 32;                       // 4*(8-g)
    while (n >= cnt) { n -= cnt; ++g; cnt = 4 * (8 - g); }
    const int span = 8 - g;
    const int i = g * 4 + n / span;
    const int j = g + n % span;
    const int b = blockIdx.y;

    __shared__ alignas(16) float q_tile[16][64];
    __shared__ alignas(16) float A_tile[16][16];

    const int tid = threadIdx.x;
    const int s0 = i * 16;
    const int e0 = j * 64;

    {
        const int r = tid >> 4, c4 = tid & 15;
        ((float4*)q_tile[r])[c4] =
            ((const float4*)(qws + ((size_t)b * Lc + s0 + r) * HSc))[c4];
        if (tid < 64) {
            const int ra = tid >> 2, ca = tid & 3;
            ((float4*)A_tile[ra])[ca] =
                ((const float4*)(Aws + ((size_t)b * Lc + s0 + ra) * OUTc))[ca];
        }
    }
    __syncthreads();

    const int gidx = tid >> 2;
    const int l = tid & 3;
    const int e = e0 + gidx;

    const float4* kk = (const float4*)(kws + ((size_t)b * Lc + e) * HSc);
    const float4 kv0 = kk[l];
    const float4 kv1 = kk[4 + l];
    const float4 kv2 = kk[8 + l];
    const float4 kv3 = kk[12 + l];
    const float4 ev  = ((const float4*)(Ews + ((size_t)b * Lc + e) * OUTc))[l];

    float* ob = out + (size_t)b * Pc * OUTc;

    #pragma unroll 8
    for (int sl = 0; sl < 16; ++sl) {
        const int s = s0 + sl;
        const float4* qq = (const float4*)q_tile[sl];
        const float4 qv0 = qq[l];
        const float4 qv1 = qq[4 + l];
        const float4 qv2 = qq[8 + l];
        const float4 qv3 = qq[12 + l];

        float sc = qv0.x * kv0.x + qv0.y * kv0.y + qv0.z * kv0.z + qv0.w * kv0.w
                 + qv1.x * kv1.x + qv1.y * kv1.y + qv1.z * kv1.z + qv1.w * kv1.w
                 + qv2.x * kv2.x + qv2.y * kv2.y + qv2.z * kv2.z + qv2.w * kv2.w
                 + qv3.x * kv3.x + qv3.y * kv3.y + qv3.z * kv3.z + qv3.w * kv3.w;
        sc += __shfl_xor(sc, 1);
        sc += __shfl_xor(sc, 2);

        if (e >= s) {
            const float4 av = ((const float4*)A_tile[sl])[l];
            const int row = s * (2 * Lc + 1 - s) / 2 + (e - s);
            floatx4 r;
            r.x = av.x + ev.x + sc;
            r.y = av.y + ev.y + sc;
            r.z = av.z + ev.z + sc;
            r.w = av.w + ev.w + sc;
            __builtin_nontemporal_store(r, (floatx4*)(ob + (size_t)row * OUTc) + l);
        }
    }
}

extern "C" void kernel_launch(void* const* d_in, const int* in_sizes, int n_in,
                              void* d_out, int out_size, void* d_ws, size_t ws_size,
                              hipStream_t stream) {
    const float* x  = (const float*)d_in[0];
    const float* Wq = (const float*)d_in[1];
    const float* bq = (const float*)d_in[2];
    const float* Wk = (const float*)d_in[3];
    const float* bk = (const float*)d_in[4];
    const float* Wb = (const float*)d_in[5];
    const float* bb = (const float*)d_in[6];

    float* ws  = (float*)d_ws;
    float* qws = ws;
    float* kws = ws + 131072;
    float* Aws = ws + 262144;
    float* Ews = ws + 294912;

    qkae_kernel<<<dim3(128), dim3(512), 0, stream>>>(
        x, Wq, Wk, bq, bk, Wb, bb, qws, kws, Aws, Ews);
    pair_kernel<<<dim3(144, 4), dim3(256), 0, stream>>>(
        qws, kws, Aws, Ews, (float*)d_out);
}

// Round 2
// 90.457 us; speedup vs baseline: 1.1064x; 1.0178x over previous
//
#include <hip/hip_runtime.h>

// Problem constants (B, L, H, HS, OUT) = (4, 512, 768, 64, 16)
#define Bc   4
#define Lc   512
#define Hc   768
#define HSc  64
#define OUTc 16
#define Pc   131328   // L*(L+1)/2
#define NTOK 2048     // B*L
#define XPITCH 776    // 768 + 8 bf16 pad -> 16B-aligned rows, banks spread

typedef float  floatx4 __attribute__((ext_vector_type(4)));
typedef short  bf16x8  __attribute__((ext_vector_type(8)));   // 8 bf16 in 4 VGPRs
typedef float  f32x4   __attribute__((ext_vector_type(4)));

// ws layout (floats): q@0 [131072], k@131072 [131072], A@262144 [32768],
//                     Eq@294912 [32768], Ek@327680 [32768]

__device__ __forceinline__ unsigned short f2bf(float f) {
    unsigned int u = __float_as_uint(f);
    return (unsigned short)((u + 0x7FFFu + ((u >> 16) & 1u)) >> 16);   // RNE
}

// Fused prep + QK-GEMM + A/E projection, q/k-split for full-CU parallelism.
// Grid 256 x 256 thr (4 waves). Block bx: mb = bx>>1 (16-token tile),
// half = bx&1 (0 = q side, 1 = k side).
// Each block stages its x-tile as bf16 in LDS (coalesced float4 + RNE cvt),
// runs a 16x64 MFMA GEMM vs Wq or Wk (B-fragments converted in-register from
// global, L2-resident), then projects:
//   q-block: A  = q @ Wb[0:64]        ; Eq = q @ Wb[128:192]
//   k-block: Ek = bb + k @ (Wb[64:128] + Wb[192:256])
// pair_kernel sums Eq[e] + Ek[e] (pure fp32 reassociation vs the fused E).
// MFMA layouts (m89/m91): A[m=lane&15][k=quad*8+j]; B[k=quad*8+j][n=lane&15];
// D: col=lane&15, row=quad*4+reg.
__global__ __launch_bounds__(256) void qkae_kernel(
    const float* __restrict__ x, const float* __restrict__ Wq,
    const float* __restrict__ Wk, const float* __restrict__ bq,
    const float* __restrict__ bk, const float* __restrict__ Wb,
    const float* __restrict__ bb,
    float* __restrict__ qws, float* __restrict__ kws,
    float* __restrict__ Aws, float* __restrict__ Eqws,
    float* __restrict__ Ekws)
{
    __shared__ alignas(16) unsigned short xs[16 * XPITCH];  // 24.25 KB
    __shared__ float lw0[64 * OUTc];                        // 4 KB
    __shared__ float lw1[64 * OUTc];                        // 4 KB
    __shared__ float lqk[16][64];                           // 4 KB

    const int tid  = threadIdx.x;
    const int mb   = blockIdx.x >> 1;
    const int half = blockIdx.x & 1;       // 0 = q, 1 = k
    const int m0   = mb * 16;

    // stage Wb slices (1024 floats each)
    if (half == 0) {
        #pragma unroll
        for (int i = 0; i < 4; ++i) {
            lw0[tid + i * 256] = Wb[tid + i * 256];           // rows 0..63   (A)
            lw1[tid + i * 256] = Wb[2048 + tid + i * 256];    // rows 128..191(Eq)
        }
    } else {
        #pragma unroll
        for (int i = 0; i < 4; ++i) {                          // rows 64..127 + 192..255
            lw0[tid + i * 256] = Wb[1024 + tid + i * 256] + Wb[3072 + tid + i * 256];
        }
    }

    // stage x tile as bf16 into padded LDS rows (3072 float4 total)
    {
        const float4* xg = (const float4*)(x + (size_t)m0 * Hc);
        #pragma unroll
        for (int i = 0; i < 12; ++i) {
            const int idx = tid + i * 256;
            const int r   = idx / 192;           // row 0..15
            const int c4  = idx - r * 192;       // float4 col 0..191
            const float4 v = xg[idx];
            *(ushort4*)(xs + r * XPITCH + c4 * 4) =
                make_ushort4(f2bf(v.x), f2bf(v.y), f2bf(v.z), f2bf(v.w));
        }
    }
    __syncthreads();

    const int w    = tid >> 6;
    const int lane = tid & 63;
    const int l15  = lane & 15;
    const int quad = lane >> 4;
    const int nq   = w * 16 + l15;           // output col 0..63 within this half

    const float* bsrc = half ? Wk : Wq;
    const unsigned short* ap = xs + l15 * XPITCH + quad * 8;

    f32x4 acc = {0.f, 0.f, 0.f, 0.f};
    #pragma unroll 4
    for (int k0 = 0; k0 < Hc; k0 += 32) {
        const bf16x8 af = *(const bf16x8*)(ap + k0);       // ds_read_b128
        const int kb = k0 + quad * 8;
        bf16x8 bf;
        #pragma unroll
        for (int j = 0; j < 8; ++j)                        // quad-coalesced dwords
            bf[j] = (short)f2bf(bsrc[(kb + j) * HSc + nq]);
        acc = __builtin_amdgcn_mfma_f32_16x16x32_bf16(af, bf, acc, 0, 0, 0);
    }

    const float bias = half ? bk[nq] : bq[nq];
    float* dst = half ? kws : qws;
    #pragma unroll
    for (int r = 0; r < 4; ++r) {
        const int t = quad * 4 + r;
        const float v = acc[r] + bias;
        dst[(size_t)(m0 + t) * HSc + nq] = v;
        lqk[t][nq] = v;
    }
    __syncthreads();

    // projection epilogue: 16 threads per token, one output col each
    const int t   = tid >> 4;        // token 0..15
    const int c   = tid & 15;
    const int tok = m0 + t;
    const float* row = lqk[t];
    if (half == 0) {
        float a = 0.f, eq = 0.f;
        #pragma unroll 8
        for (int h = 0; h < 64; ++h) {
            const float rv = row[h];
            a  += rv * lw0[h * OUTc + c];
            eq += rv * lw1[h * OUTc + c];
        }
        Aws[(size_t)tok * OUTc + c]  = a;
        Eqws[(size_t)tok * OUTc + c] = eq;
    } else {
        float ek = bb[c];
        #pragma unroll 8
        for (int h = 0; h < 64; ++h)
            ek += row[h] * lw0[h * OUTc + c];
        Ekws[(size_t)tok * OUTc + c] = ek;
    }
}

// Pair kernel: 16 s x 64 e tiles, only the 144 active upper-triangular tiles
// per batch (decoded in-kernel). Grid (144, 4): x = linear tile id, y = batch.
__global__ __launch_bounds__(256) void pair_kernel(
    const float* __restrict__ qws, const float* __restrict__ kws,
    const float* __restrict__ Aws, const float* __restrict__ Eqws,
    const float* __restrict__ Ekws,
    float* __restrict__ out)
{
    // decode linear tile id -> (i = s-tile 0..31, j = e-tile 0..7), j >= i>>2
    int n = blockIdx.x;
    int g = 0;
    int cnt = 32;                       // 4*(8-g)
    while (n >= cnt) { n -= cnt; ++g; cnt = 4 * (8 - g); }
    const int span = 8 - g;
    const int i = g * 4 + n / span;
    const int j = g + n % span;
    const int b = blockIdx.y;

    __shared__ alignas(16) float q_tile[16][64];
    __shared__ alignas(16) float A_tile[16][16];

    const int tid = threadIdx.x;
    const int s0 = i * 16;
    const int e0 = j * 64;

    {
        const int r = tid >> 4, c4 = tid & 15;
        ((float4*)q_tile[r])[c4] =
            ((const float4*)(qws + ((size_t)b * Lc + s0 + r) * HSc))[c4];
        if (tid < 64) {
            const int ra = tid >> 2, ca = tid & 3;
            ((float4*)A_tile[ra])[ca] =
                ((const float4*)(Aws + ((size_t)b * Lc + s0 + ra) * OUTc))[ca];
        }
    }
    __syncthreads();

    const int gidx = tid >> 2;
    const int l = tid & 3;
    const int e = e0 + gidx;

    const float4* kk = (const float4*)(kws + ((size_t)b * Lc + e) * HSc);
    const float4 kv0 = kk[l];
    const float4 kv1 = kk[4 + l];
    const float4 kv2 = kk[8 + l];
    const float4 kv3 = kk[12 + l];
    const float4 evq = ((const float4*)(Eqws + ((size_t)b * Lc + e) * OUTc))[l];
    const float4 evk = ((const float4*)(Ekws + ((size_t)b * Lc + e) * OUTc))[l];
    const float4 ev  = make_float4(evq.x + evk.x, evq.y + evk.y,
                                   evq.z + evk.z, evq.w + evk.w);

    float* ob = out + (size_t)b * Pc * OUTc;

    #pragma unroll 8
    for (int sl = 0; sl < 16; ++sl) {
        const int s = s0 + sl;
        const float4* qq = (const float4*)q_tile[sl];
        const float4 qv0 = qq[l];
        const float4 qv1 = qq[4 + l];
        const float4 qv2 = qq[8 + l];
        const float4 qv3 = qq[12 + l];

        float sc = qv0.x * kv0.x + qv0.y * kv0.y + qv0.z * kv0.z + qv0.w * kv0.w
                 + qv1.x * kv1.x + qv1.y * kv1.y + qv1.z * kv1.z + qv1.w * kv1.w
                 + qv2.x * kv2.x + qv2.y * kv2.y + qv2.z * kv2.z + qv2.w * kv2.w
                 + qv3.x * kv3.x + qv3.y * kv3.y + qv3.z * kv3.z + qv3.w * kv3.w;
        sc += __shfl_xor(sc, 1);
        sc += __shfl_xor(sc, 2);

        if (e >= s) {
            const float4 av = ((const float4*)A_tile[sl])[l];
            const int row = s * (2 * Lc + 1 - s) / 2 + (e - s);
            floatx4 r;
            r.x = av.x + ev.x + sc;
            r.y = av.y + ev.y + sc;
            r.z = av.z + ev.z + sc;
            r.w = av.w + ev.w + sc;
            __builtin_nontemporal_store(r, (floatx4*)(ob + (size_t)row * OUTc) + l);
        }
    }
}

extern "C" void kernel_launch(void* const* d_in, const int* in_sizes, int n_in,
                              void* d_out, int out_size, void* d_ws, size_t ws_size,
                              hipStream_t stream) {
    const float* x  = (const float*)d_in[0];
    const float* Wq = (const float*)d_in[1];
    const float* bq = (const float*)d_in[2];
    const float* Wk = (const float*)d_in[3];
    const float* bk = (const float*)d_in[4];
    const float* Wb = (const float*)d_in[5];
    const float* bb = (const float*)d_in[6];

    float* ws   = (float*)d_ws;
    float* qws  = ws;
    float* kws  = ws + 131072;
    float* Aws  = ws + 262144;
    float* Eqws = ws + 294912;
    float* Ekws = ws + 327680;

    qkae_kernel<<<dim3(256), dim3(256), 0, stream>>>(
        x, Wq, Wk, bq, bk, Wb, bb, qws, kws, Aws, Eqws, Ekws);
    pair_kernel<<<dim3(144, 4), dim3(256), 0, stream>>>(
        qws, kws, Aws, Eqws, Ekws, (float*)d_out);
}